// Round 2
// baseline (807.677 us; speedup 1.0000x reference)
//
#include <hip/hip_runtime.h>

#define NN 8192
#define CC 512
#define DKK 64

typedef float f32x4 __attribute__((ext_vector_type(4)));
typedef float f32x16 __attribute__((ext_vector_type(16)));
typedef _Float16 f16x8 __attribute__((ext_vector_type(8)));
typedef _Float16 f16x4 __attribute__((ext_vector_type(4)));

__device__ __forceinline__ f32x4 mfma16(f16x8 a, f16x8 b, f32x4 c) {
    return __builtin_amdgcn_mfma_f32_16x16x32_f16(a, b, c, 0, 0, 0);
}
__device__ __forceinline__ f32x16 mfma32(f16x8 a, f16x8 b, f32x16 c) {
    return __builtin_amdgcn_mfma_f32_32x32x16_f16(a, b, c, 0, 0, 0);
}

// ---- transpose + f16-convert weights: W[512][Nout] f32 -> Wt[Nout][512] f16
__global__ void wtrans_kernel(const float* __restrict__ W, _Float16* __restrict__ Wt, int Nout) {
    int idx = blockIdx.x * 256 + threadIdx.x;
    if (idx >= Nout * 512) return;
    int n = idx >> 9;
    int k = idx & 511;
    Wt[idx] = (_Float16)W[k * Nout + n];
}

// ---- Q/K projection: X[N][512] f32 x Wt[64][512] -> O[N][64] f16 (row-major)
__global__ __launch_bounds__(256) void proj_qk_kernel(
    const float* __restrict__ im1, const float* __restrict__ im2,
    const _Float16* __restrict__ Wqt, const _Float16* __restrict__ Wkt,
    _Float16* __restrict__ Q1, _Float16* __restrict__ K1,
    _Float16* __restrict__ Q2, _Float16* __restrict__ K2)
{
    const float* X = blockIdx.y ? im2 : im1;
    const _Float16* Wt = blockIdx.z ? Wkt : Wqt;
    _Float16* O = blockIdx.y ? (blockIdx.z ? K2 : Q2) : (blockIdx.z ? K1 : Q1);
    const int lane = threadIdx.x & 63, wave = threadIdx.x >> 6;
    const int n16 = lane & 15, quad = lane >> 4;
    const int arow = blockIdx.x * 64 + wave * 16 + n16;

    f32x4 acc[4];
#pragma unroll
    for (int i = 0; i < 4; i++) acc[i] = (f32x4){0.f, 0.f, 0.f, 0.f};

    const float* xbase = X + (size_t)arow * 512 + quad * 8;
    for (int k0 = 0; k0 < 512; k0 += 32) {
        f32x4 xa = *(const f32x4*)(xbase + k0);
        f32x4 xb = *(const f32x4*)(xbase + k0 + 4);
        f16x8 a;
#pragma unroll
        for (int j = 0; j < 4; j++) { a[j] = (_Float16)xa[j]; a[4 + j] = (_Float16)xb[j]; }
#pragma unroll
        for (int t = 0; t < 4; t++) {
            f16x8 b = *(const f16x8*)(Wt + (size_t)(t * 16 + n16) * 512 + k0 + quad * 8);
            acc[t] = mfma16(a, b, acc[t]);
        }
    }
    const int rbase = blockIdx.x * 64 + wave * 16 + quad * 4;
#pragma unroll
    for (int t = 0; t < 4; t++)
#pragma unroll
        for (int r = 0; r < 4; r++)
            O[(size_t)(rbase + r) * 64 + t * 16 + n16] = (_Float16)acc[t][r];
}

// ---- V projection via operand swap: computes Vt[c][n] = (X @ Wv)^T directly.
// Block: 32 im-rows (n0), 4 waves x 128 c-cols each. Coalesced b16 stores.
__global__ __launch_bounds__(256) void proj_vt_kernel(
    const float* __restrict__ im1, const float* __restrict__ im2,
    const _Float16* __restrict__ Wvt,
    _Float16* __restrict__ V1t, _Float16* __restrict__ V2t)
{
    const float* X = blockIdx.y ? im2 : im1;
    _Float16* Vt = blockIdx.y ? V2t : V1t;
    const int n0 = blockIdx.x * 32;
    const int tid = threadIdx.x;
    const int lane = tid & 63, wave = tid >> 6;
    const int l31 = lane & 31, lhi = lane >> 5;

    __shared__ __align__(16) _Float16 Xlds[32 * 512];

    // stage X tile [32 n][512 k] as f16, XOR-swizzled 16B chunks
#pragma unroll
    for (int i = 0; i < 8; i++) {
        const int n = tid >> 3;
        const int chunk = (tid & 7) + 8 * i;
        const float* xp = X + (size_t)(n0 + n) * CC + chunk * 8;
        f32x4 x0 = *(const f32x4*)xp;
        f32x4 x1 = *(const f32x4*)(xp + 4);
        f16x8 d;
#pragma unroll
        for (int j = 0; j < 4; j++) { d[j] = (_Float16)x0[j]; d[4 + j] = (_Float16)x1[j]; }
        *(f16x8*)&Xlds[n * 512 + ((chunk ^ (n & 7)) * 8)] = d;
    }
    __syncthreads();

    f32x16 acc[4];
#pragma unroll
    for (int t = 0; t < 4; t++)
#pragma unroll
        for (int r = 0; r < 16; r++) acc[t][r] = 0.f;

    for (int ks = 0; ks < 32; ks++) {
        f16x8 xb = *(const f16x8*)&Xlds[l31 * 512 + (((2 * ks + lhi) ^ (l31 & 7)) * 8)];
#pragma unroll
        for (int ct = 0; ct < 4; ct++) {
            const _Float16* wp = Wvt + (size_t)(128 * wave + 32 * ct + l31) * CC + 16 * ks + 8 * lhi;
            acc[ct] = mfma32(*(const f16x8*)wp, xb, acc[ct]);
        }
    }
#pragma unroll
    for (int ct = 0; ct < 4; ct++)
#pragma unroll
        for (int r = 0; r < 16; r++) {
            const int c = 128 * wave + 32 * ct + (r & 3) + 8 * (r >> 2) + 4 * lhi;
            Vt[(size_t)c * NN + n0 + l31] = (_Float16)acc[ct][r];
        }
}

// ---- fused flash cross-attention (S^T formulation, producer/consumer waves)
// grid (128, 2): x = q-tile of 64 rows, y = image. 512 threads = 8 waves:
// waves 0,1: QK+softmax+P (q-halves); waves 2,3: K-stagers; 4-7: V-stagers.
// PV: waves 0..3 (c-quarters). V/K double-buffered, XOR-swizzled (no pad).
__global__ __launch_bounds__(512) void flash2_kernel(
    const _Float16* __restrict__ Q1, const _Float16* __restrict__ K1,
    const _Float16* __restrict__ Q2, const _Float16* __restrict__ K2,
    const _Float16* __restrict__ V1t, const _Float16* __restrict__ V2t,
    const float* __restrict__ im1, const float* __restrict__ im2,
    float* __restrict__ out)
{
    const int img = blockIdx.y;
    const _Float16* Q = img ? Q1 : Q2;
    const _Float16* K = img ? K2 : K1;
    const _Float16* Vt = img ? V2t : V1t;
    const float* res = img ? im2 : im1;
    float* o = out + (size_t)img * NN * CC;

    __shared__ __align__(16) _Float16 Vlds[2][512 * 64];  // 128 KB
    __shared__ __align__(16) _Float16 Klds[2][64 * 64];   //  16 KB
    __shared__ __align__(16) _Float16 Plds[64 * 64];      //   8 KB
    __shared__ float alphaLds[64];
    __shared__ float linvLds[64];
    float* Olds = (float*)&Vlds[0][0];                    // epilogue alias (67 KB)

    const int tid = threadIdx.x;
    const int lane = tid & 63, wave = tid >> 6;
    const int l31 = lane & 31, lhi = lane >> 5;
    const int qbase = blockIdx.x * 64;
    const bool isQK = (wave < 2);
    const bool isPV = (wave < 4);

    // Q B-frags preload (waves 0,1): B[k=dk][n=q=lane&31]
    f16x8 qf[4];
    if (isQK) {
        const _Float16* qp = Q + (size_t)(qbase + 32 * wave + l31) * DKK + 8 * lhi;
#pragma unroll
        for (int k = 0; k < 4; k++) qf[k] = *(const f16x8*)(qp + 16 * k);
    }

    f32x16 acc[8];  // [ct*2 + qt], O^T tiles (PV waves)
#pragma unroll
    for (int t = 0; t < 8; t++)
#pragma unroll
        for (int r = 0; r < 16; r++) acc[t][r] = 0.f;
    float m_prev = -3e38f, l_run = 0.f;

    // ---- pre-stage tile 0 into buf 0 (all 512 threads)
    {
        const int jr = tid >> 3, jc = tid & 7;
#pragma unroll
        for (int i = 0; i < 8; i++) {
            const int c = i * 64 + jr;
            f16x8 d = *(const f16x8*)(Vt + (size_t)c * NN + jc * 8);
            *(f16x8*)&Vlds[0][c * 64 + ((jc ^ (c & 7)) * 8)] = d;
        }
        f16x8 dk = *(const f16x8*)(K + (size_t)jr * DKK + jc * 8);
        *(f16x8*)&Klds[0][jr * 64 + ((jc ^ (jr & 7)) * 8)] = dk;
    }
    __syncthreads();

    for (int it = 0; it < 128; ++it) {
        const int buf = it & 1;
        // ---- phase 1: QK (waves 0,1) || stage tile it+1 (waves 2..7)
        if (isQK) {
            f32x16 s[2];
#pragma unroll
            for (int a = 0; a < 2; a++)
#pragma unroll
                for (int r = 0; r < 16; r++) s[a][r] = 0.f;
#pragma unroll
            for (int a = 0; a < 2; a++)
#pragma unroll
                for (int k = 0; k < 4; k++) {
                    const int row = 32 * a + l31;
                    f16x8 kf = *(const f16x8*)&Klds[buf][row * 64 + (((2 * k + lhi) ^ (l31 & 7)) * 8)];
                    s[a] = mfma32(kf, qf[k], s[a]);
                }
            // per-lane online softmax (q = 32*wave + l31, kv in regs)
            float mx = -3e38f;
#pragma unroll
            for (int a = 0; a < 2; a++)
#pragma unroll
                for (int r = 0; r < 16; r++) mx = fmaxf(mx, s[a][r]);
            mx = fmaxf(mx, __shfl_xor(mx, 32));
            const float mnew = fmaxf(m_prev, mx);
            const float alpha = __expf(m_prev - mnew);
            float ls = 0.f;
#pragma unroll
            for (int a = 0; a < 2; a++)
#pragma unroll
                for (int r = 0; r < 16; r++) {
                    float pv = __expf(s[a][r] - mnew);
                    ls += pv;
                    s[a][r] = pv;
                }
            ls += __shfl_xor(ls, 32);
            l_run = l_run * alpha + ls;
            m_prev = mnew;
            if (lane < 32) alphaLds[32 * wave + lane] = alpha;
            // write P[q][kv] (b64, swizzled): kv = 32a + 8g + 4*lhi + u
            const int q = 32 * wave + l31;
#pragma unroll
            for (int a = 0; a < 2; a++)
#pragma unroll
                for (int g = 0; g < 4; g++) {
                    f16x4 p4;
#pragma unroll
                    for (int u = 0; u < 4; u++) p4[u] = (_Float16)s[a][g * 4 + u];
                    const int chunk = 4 * a + g;
                    *(f16x4*)&Plds[q * 64 + ((chunk ^ (q & 7)) * 8) + 4 * lhi] = p4;
                }
        } else if (wave < 4) {
            if (it + 1 < 128) {
                const int j = (wave - 2) * 64 + lane;  // 0..127
                const int kvn = (it + 1) * 64;
                const int jc = j & 7;
#pragma unroll
                for (int i = 0; i < 4; i++) {
                    const int kvr = i * 16 + (j >> 3);
                    f16x8 d = *(const f16x8*)(K + (size_t)(kvn + kvr) * DKK + jc * 8);
                    *(f16x8*)&Klds[buf ^ 1][kvr * 64 + ((jc ^ (kvr & 7)) * 8)] = d;
                }
            }
        } else {
            if (it + 1 < 128) {
                const int j = (wave - 4) * 64 + lane;  // 0..255
                const int kvn = (it + 1) * 64;
                const int jc = j & 7;
#pragma unroll
                for (int i = 0; i < 16; i++) {
                    const int c = i * 32 + (j >> 3);
                    f16x8 d = *(const f16x8*)(Vt + (size_t)c * NN + kvn + jc * 8);
                    *(f16x8*)&Vlds[buf ^ 1][c * 64 + ((jc ^ (c & 7)) * 8)] = d;
                }
            }
        }
        __syncthreads();  // P/alpha ready; stage complete
        // ---- phase 2: PV (waves 0..3, c-quarter each)
        if (isPV) {
            const float a0 = alphaLds[l31];
            const float a1 = alphaLds[32 + l31];
            if (!__all((a0 == 1.f) & (a1 == 1.f))) {
#pragma unroll
                for (int ct = 0; ct < 4; ct++)
#pragma unroll
                    for (int r = 0; r < 16; r++) {
                        acc[ct * 2 + 0][r] *= a0;
                        acc[ct * 2 + 1][r] *= a1;
                    }
            }
#pragma unroll
            for (int k = 0; k < 4; k++) {
                const int swz = ((2 * k + lhi) ^ (l31 & 7)) * 8;
                f16x8 pb0 = *(const f16x8*)&Plds[l31 * 64 + swz];
                f16x8 pb1 = *(const f16x8*)&Plds[(32 + l31) * 64 + swz];
#pragma unroll
                for (int ct = 0; ct < 4; ct++) {
                    f16x8 va = *(const f16x8*)&Vlds[buf][(128 * wave + 32 * ct + l31) * 64 + swz];
                    acc[ct * 2 + 0] = mfma32(va, pb0, acc[ct * 2 + 0]);
                    acc[ct * 2 + 1] = mfma32(va, pb1, acc[ct * 2 + 1]);
                }
            }
        }
        __syncthreads();  // PV done: next stage may overwrite buf, P, alpha
    }

    // ---- epilogue: normalize, transpose via LDS, add residual, store fp32
    if (isQK && lane < 32) linvLds[32 * wave + lane] = 1.f / l_run;
    __syncthreads();
#pragma unroll
    for (int qt = 0; qt < 2; ++qt) {
        if (isPV) {
            const float lv = linvLds[32 * qt + l31];
#pragma unroll
            for (int ct = 0; ct < 4; ct++)
#pragma unroll
                for (int r = 0; r < 16; r++) {
                    const int c = 128 * wave + 32 * ct + (r & 3) + 8 * (r >> 2) + 4 * lhi;
                    Olds[l31 * 524 + c] = acc[ct * 2 + qt][r] * lv;
                }
        }
        __syncthreads();
        const int qrow = tid >> 4, cb = tid & 15;
        const size_t grow = (size_t)(qbase + 32 * qt + qrow);
#pragma unroll
        for (int i = 0; i < 8; i++) {
            const int c4 = (cb + 16 * i) * 4;
            f32x4 v = *(const f32x4*)&Olds[qrow * 524 + c4];
            f32x4 rr = *(const f32x4*)(res + grow * CC + c4);
            v += rr;
            *(f32x4*)(o + grow * CC + c4) = v;
        }
        __syncthreads();
    }
}

extern "C" void kernel_launch(void* const* d_in, const int* in_sizes, int n_in,
                              void* d_out, int out_size, void* d_ws, size_t ws_size,
                              hipStream_t stream) {
    const float* im1 = (const float*)d_in[0];
    const float* im2 = (const float*)d_in[1];
    const float* Wq  = (const float*)d_in[2];
    const float* Wk  = (const float*)d_in[3];
    const float* Wv  = (const float*)d_in[4];
    float* out = (float*)d_out;

    _Float16* w = (_Float16*)d_ws;
    _Float16* Wqt = w;                      // 64*512
    _Float16* Wkt = Wqt + 64 * 512;         // 64*512
    _Float16* Wvt = Wkt + 64 * 512;         // 512*512
    _Float16* Q1  = Wvt + 512 * 512;        // 8192*64 each
    _Float16* K1  = Q1 + NN * DKK;
    _Float16* Q2  = K1 + NN * DKK;
    _Float16* K2  = Q2 + NN * DKK;
    _Float16* V1t = K2 + NN * DKK;          // [512][8192] each
    _Float16* V2t = V1t + (size_t)CC * NN;

    wtrans_kernel<<<128, 256, 0, stream>>>(Wq, Wqt, 64);
    wtrans_kernel<<<128, 256, 0, stream>>>(Wk, Wkt, 64);
    wtrans_kernel<<<1024, 256, 0, stream>>>(Wv, Wvt, 512);
    proj_qk_kernel<<<dim3(128, 2, 2), 256, 0, stream>>>(im1, im2, Wqt, Wkt, Q1, K1, Q2, K2);
    proj_vt_kernel<<<dim3(256, 2), 256, 0, stream>>>(im1, im2, Wvt, V1t, V2t);
    flash2_kernel<<<dim3(128, 2), 512, 0, stream>>>(Q1, K1, Q2, K2, V1t, V2t, im1, im2, out);
}

// Round 3
// 466.560 us; speedup vs baseline: 1.7311x; 1.7311x over previous
//
#include <hip/hip_runtime.h>

#define NN 8192
#define CC 512
#define DKK 64

typedef float f32x4 __attribute__((ext_vector_type(4)));
typedef float f32x16 __attribute__((ext_vector_type(16)));
typedef _Float16 f16x8 __attribute__((ext_vector_type(8)));
typedef _Float16 f16x4 __attribute__((ext_vector_type(4)));

__device__ __forceinline__ f32x4 mfma16(f16x8 a, f16x8 b, f32x4 c) {
    return __builtin_amdgcn_mfma_f32_16x16x32_f16(a, b, c, 0, 0, 0);
}
__device__ __forceinline__ f32x16 mfma32(f16x8 a, f16x8 b, f32x16 c) {
    return __builtin_amdgcn_mfma_f32_32x32x16_f16(a, b, c, 0, 0, 0);
}

// ---- transpose + f16-convert weights: W[512][Nout] f32 -> Wt[Nout][512] f16
__global__ void wtrans_kernel(const float* __restrict__ W, _Float16* __restrict__ Wt, int Nout) {
    int idx = blockIdx.x * 256 + threadIdx.x;
    if (idx >= Nout * 512) return;
    int n = idx >> 9;
    int k = idx & 511;
    Wt[idx] = (_Float16)W[k * Nout + n];
}

// ---- fused Q+K projection: X[N][512] f32 -> Q[N][64], K[N][64] f16 row-major.
// Weights (Wqt|Wkt = 128 rows x 512) staged in LDS; X read once.
__global__ __launch_bounds__(256) void proj_qk2_kernel(
    const float* __restrict__ im1, const float* __restrict__ im2,
    const _Float16* __restrict__ Wqt, const _Float16* __restrict__ Wkt,
    _Float16* __restrict__ Q1, _Float16* __restrict__ K1,
    _Float16* __restrict__ Q2, _Float16* __restrict__ K2)
{
    const float* X = blockIdx.y ? im2 : im1;
    _Float16* Q = blockIdx.y ? Q2 : Q1;
    _Float16* K = blockIdx.y ? K2 : K1;

    __shared__ __align__(16) _Float16 Wlds[128 * 512];  // 128 KB

    const int tid = threadIdx.x;
    const int lane = tid & 63, wave = tid >> 6;
    const int n16 = lane & 15, quad = lane >> 4;

    // stage Wqt (rows 0-63) + Wkt (rows 64-127), chunk-swizzled
#pragma unroll
    for (int i = 0; i < 32; i++) {
        const int idx = tid + 256 * i;
        const int row = idx >> 6, ch = idx & 63;
        const _Float16* src = (row < 64) ? (Wqt + (size_t)row * 512 + ch * 8)
                                         : (Wkt + (size_t)(row - 64) * 512 + ch * 8);
        *(f16x8*)&Wlds[row * 512 + ((ch ^ (row & 7)) * 8)] = *(const f16x8*)src;
    }
    __syncthreads();

    const int arow = blockIdx.x * 64 + wave * 16 + n16;
    f32x4 acc[8];
#pragma unroll
    for (int i = 0; i < 8; i++) acc[i] = (f32x4){0.f, 0.f, 0.f, 0.f};

    const float* xbase = X + (size_t)arow * 512 + quad * 8;
    for (int kk = 0; kk < 16; kk++) {
        f32x4 xa = *(const f32x4*)(xbase + kk * 32);
        f32x4 xb = *(const f32x4*)(xbase + kk * 32 + 4);
        f16x8 afrag;
#pragma unroll
        for (int j = 0; j < 4; j++) { afrag[j] = (_Float16)xa[j]; afrag[4 + j] = (_Float16)xb[j]; }
#pragma unroll
        for (int t = 0; t < 8; t++) {
            const int row = t * 16 + n16;
            f16x8 b = *(const f16x8*)&Wlds[row * 512 + (((4 * kk + quad) ^ (row & 7)) * 8)];
            acc[t] = mfma16(afrag, b, acc[t]);
        }
    }
    const int rbase = blockIdx.x * 64 + wave * 16 + quad * 4;
#pragma unroll
    for (int t = 0; t < 4; t++)
#pragma unroll
        for (int r = 0; r < 4; r++) {
            Q[(size_t)(rbase + r) * 64 + t * 16 + n16] = (_Float16)acc[t][r];
            K[(size_t)(rbase + r) * 64 + t * 16 + n16] = (_Float16)acc[4 + t][r];
        }
}

// ---- V projection, kv-tiled transposed output: Vb[tile][512][64] f16
__global__ __launch_bounds__(256) void proj_vt_kernel(
    const float* __restrict__ im1, const float* __restrict__ im2,
    const _Float16* __restrict__ Wvt,
    _Float16* __restrict__ V1b, _Float16* __restrict__ V2b)
{
    const float* X = blockIdx.y ? im2 : im1;
    _Float16* Vb = blockIdx.y ? V2b : V1b;
    const int n0 = blockIdx.x * 32;
    const int tid = threadIdx.x;
    const int lane = tid & 63, wave = tid >> 6;
    const int l31 = lane & 31, lhi = lane >> 5;

    __shared__ __align__(16) _Float16 Xlds[32 * 512];

#pragma unroll
    for (int i = 0; i < 8; i++) {
        const int n = tid >> 3;
        const int chunk = (tid & 7) + 8 * i;
        const float* xp = X + (size_t)(n0 + n) * CC + chunk * 8;
        f32x4 x0 = *(const f32x4*)xp;
        f32x4 x1 = *(const f32x4*)(xp + 4);
        f16x8 d;
#pragma unroll
        for (int j = 0; j < 4; j++) { d[j] = (_Float16)x0[j]; d[4 + j] = (_Float16)x1[j]; }
        *(f16x8*)&Xlds[n * 512 + ((chunk ^ (n & 7)) * 8)] = d;
    }
    __syncthreads();

    f32x16 acc[4];
#pragma unroll
    for (int t = 0; t < 4; t++)
#pragma unroll
        for (int r = 0; r < 16; r++) acc[t][r] = 0.f;

    for (int ks = 0; ks < 32; ks++) {
        f16x8 xb = *(const f16x8*)&Xlds[l31 * 512 + (((2 * ks + lhi) ^ (l31 & 7)) * 8)];
#pragma unroll
        for (int ct = 0; ct < 4; ct++) {
            const _Float16* wp = Wvt + (size_t)(128 * wave + 32 * ct + l31) * CC + 16 * ks + 8 * lhi;
            acc[ct] = mfma32(*(const f16x8*)wp, xb, acc[ct]);
        }
    }
    const int tile = n0 >> 6;
    const int within = n0 & 32;
#pragma unroll
    for (int ct = 0; ct < 4; ct++)
#pragma unroll
        for (int r = 0; r < 16; r++) {
            const int c = 128 * wave + 32 * ct + (r & 3) + 8 * (r >> 2) + 4 * lhi;
            Vb[(size_t)tile * 32768 + c * 64 + within + l31] = (_Float16)acc[ct][r];
        }
}

// ---- flash cross-attention v3: uniform waves, split-K softmax groups,
// V/K A-frags direct from global (L2), LDS only for P + softmax scalars.
// grid (128, 2), 512 threads = 8 waves: g = wave>>2 (kv-parity group),
// wg = wave&3; b = wg&1 (q-half for QK), a = wg>>1 (kv-half for QK);
// PV: every wave owns c-quarter 128*wg.
__global__ __launch_bounds__(512) void flash3_kernel(
    const _Float16* __restrict__ Q1, const _Float16* __restrict__ K1,
    const _Float16* __restrict__ Q2, const _Float16* __restrict__ K2,
    const _Float16* __restrict__ V1b, const _Float16* __restrict__ V2b,
    const float* __restrict__ im1, const float* __restrict__ im2,
    float* __restrict__ out)
{
    const int img = blockIdx.y;
    const _Float16* Q = img ? Q1 : Q2;
    const _Float16* K = img ? K2 : K1;
    const _Float16* Vb = img ? V2b : V1b;
    const float* res = img ? im2 : im1;
    float* o = out + (size_t)img * NN * CC;

    // big buffer: P[2][64][64] f16 (16 KB) during loop; Olds f32[64][516] in epilogue
    __shared__ __align__(16) char smem[64 * 516 * 4];  // 132096 B
    __shared__ float mPart[2][2][64];
    __shared__ float aLds[2][64];
    __shared__ float mFin[2][64];
    __shared__ float lFin[2][2][64];

    const int tid = threadIdx.x;
    const int lane = tid & 63, wave = tid >> 6;
    const int l31 = lane & 31, lhi = lane >> 5;
    const int g = wave >> 2, wg = wave & 3;
    const int b = wg & 1, a = wg >> 1;
    const int qbase = blockIdx.x * 64;

    _Float16* Pg = (_Float16*)smem + g * 64 * 64;

    // Q B-frags: lane l31 = q (n-dim), k = 16*kstep + 8*lhi + j
    f16x8 qf[4];
    {
        const _Float16* qp = Q + (size_t)(qbase + 32 * b + l31) * DKK + 8 * lhi;
#pragma unroll
        for (int k = 0; k < 4; k++) qf[k] = *(const f16x8*)(qp + 16 * k);
    }

    f32x16 acc[8];  // [ct*2 + qt]: O^T tile rows c=128*wg+32*ct+..., col q=32*qt+l31
#pragma unroll
    for (int t = 0; t < 8; t++)
#pragma unroll
        for (int r = 0; r < 16; r++) acc[t][r] = 0.f;
    float m_prev = -3e38f, l_run = 0.f;

    const int swz = l31 & 7;  // P row swizzle key (same for rows l31 and 32+l31)

    for (int s = 0; s < 64; s++) {
        const int t = 2 * s + g;
        const int kvb = t * 64;

        // ---- QK: S^T quarter [32 kv (a-half)][32 q (b-half)], K direct from global
        f32x16 sA;
#pragma unroll
        for (int r = 0; r < 16; r++) sA[r] = 0.f;
        {
            const _Float16* kp = K + (size_t)(kvb + 32 * a + l31) * DKK + 8 * lhi;
#pragma unroll
            for (int k = 0; k < 4; k++) {
                f16x8 kf = *(const f16x8*)(kp + 16 * k);
                sA = mfma32(kf, qf[k], sA);
            }
        }
        float mx = -3e38f;
#pragma unroll
        for (int r = 0; r < 16; r++) mx = fmaxf(mx, sA[r]);
        mx = fmaxf(mx, __shfl_xor(mx, 32));
        if (lane < 32) mPart[g][a][32 * b + lane] = mx;
        __syncthreads();  // b1: mPart ready (also: prev slot's P reads all done)

        // prefetch k=0 V-frags (independent of P)
        f16x8 va0[4];
#pragma unroll
        for (int ct = 0; ct < 4; ct++)
            va0[ct] = *(const f16x8*)(Vb + (size_t)t * 32768 + (128 * wg + 32 * ct + l31) * 64 + 8 * lhi);

        const float mo = mPart[g][a ^ 1][32 * b + l31];
        const float mnew = fmaxf(fmaxf(m_prev, mx), mo);
        const float alpha = __expf(m_prev - mnew);
        float ls = 0.f;
#pragma unroll
        for (int r = 0; r < 16; r++) {
            float p = __expf(sA[r] - mnew);
            ls += p;
            sA[r] = p;
        }
        ls += __shfl_xor(ls, 32);
        l_run = l_run * alpha + ls;  // own kv-half only; halves summed in epilogue
        m_prev = mnew;
        if (a == 0 && lane < 32) aLds[g][32 * b + lane] = alpha;
        // P write: row q=32b+l31, kv chunks 4a+gg, offset 4*lhi inside chunk
        {
            const int q = 32 * b + l31;
#pragma unroll
            for (int gg = 0; gg < 4; gg++) {
                f16x4 p4;
#pragma unroll
                for (int u = 0; u < 4; u++) p4[u] = (_Float16)sA[gg * 4 + u];
                *(f16x4*)&Pg[q * 64 + (((4 * a + gg) ^ (q & 7)) * 8) + 4 * lhi] = p4;
            }
        }
        __syncthreads();  // b2: P + alpha complete

        // ---- PV: acc rescale + O^T += V^T P^T, V direct from global
        {
            const float a0 = aLds[g][l31];
            const float a1 = aLds[g][32 + l31];
            if (!__all((a0 == 1.f) & (a1 == 1.f))) {
#pragma unroll
                for (int ct = 0; ct < 4; ct++)
#pragma unroll
                    for (int r = 0; r < 16; r++) {
                        acc[ct * 2 + 0][r] *= a0;
                        acc[ct * 2 + 1][r] *= a1;
                    }
            }
#pragma unroll
            for (int k = 0; k < 4; k++) {
                const int psw = ((2 * k + lhi) ^ swz) * 8;
                f16x8 pb0 = *(const f16x8*)&Pg[l31 * 64 + psw];
                f16x8 pb1 = *(const f16x8*)&Pg[(32 + l31) * 64 + psw];
#pragma unroll
                for (int ct = 0; ct < 4; ct++) {
                    f16x8 va;
                    if (k == 0) va = va0[ct];
                    else va = *(const f16x8*)(Vb + (size_t)t * 32768 + (128 * wg + 32 * ct + l31) * 64 + 16 * k + 8 * lhi);
                    acc[ct * 2 + 0] = mfma32(va, pb0, acc[ct * 2 + 0]);
                    acc[ct * 2 + 1] = mfma32(va, pb1, acc[ct * 2 + 1]);
                }
            }
        }
        // next slot's b1 protects P from early overwrite
    }

    // ---- epilogue: merge the two kv-parity groups, add residual, store
    if (a == 0 && lane < 32) mFin[g][32 * b + lane] = m_prev;
    if (lane < 32) lFin[g][a][32 * b + lane] = l_run;
    __syncthreads();

    float fac[2];
#pragma unroll
    for (int qt = 0; qt < 2; qt++) {
        const int q = 32 * qt + l31;
        const float m0 = mFin[0][q], m1 = mFin[1][q];
        const float l0 = lFin[0][0][q] + lFin[0][1][q];
        const float l1 = lFin[1][0][q] + lFin[1][1][q];
        const float M = fmaxf(m0, m1);
        const float e0 = __expf(m0 - M), e1 = __expf(m1 - M);
        const float den = e0 * l0 + e1 * l1;
        fac[qt] = (g ? e1 : e0) / den;
    }

    float* Olds = (float*)smem;  // [64][516]
    if (g == 0) {
#pragma unroll
        for (int ct = 0; ct < 4; ct++)
#pragma unroll
            for (int qt = 0; qt < 2; qt++)
#pragma unroll
                for (int r = 0; r < 16; r++) {
                    const int c = 128 * wg + 32 * ct + (r & 3) + 8 * (r >> 2) + 4 * lhi;
                    Olds[(32 * qt + l31) * 516 + c] = acc[ct * 2 + qt][r] * fac[qt];
                }
    }
    __syncthreads();
    if (g == 1) {
#pragma unroll
        for (int ct = 0; ct < 4; ct++)
#pragma unroll
            for (int qt = 0; qt < 2; qt++)
#pragma unroll
                for (int r = 0; r < 16; r++) {
                    const int c = 128 * wg + 32 * ct + (r & 3) + 8 * (r >> 2) + 4 * lhi;
                    Olds[(32 * qt + l31) * 516 + c] += acc[ct * 2 + qt][r] * fac[qt];
                }
    }
    __syncthreads();

    {
        const int q = tid >> 3;
        const size_t grow = (size_t)(qbase + q);
#pragma unroll
        for (int i = 0; i < 16; i++) {
            const int cw = ((tid & 7) + 8 * i) * 4;
            f32x4 v = *(const f32x4*)&Olds[q * 516 + cw];
            f32x4 rr = *(const f32x4*)(res + grow * CC + cw);
            v += rr;
            *(f32x4*)(o + grow * CC + cw) = v;
        }
    }
}

extern "C" void kernel_launch(void* const* d_in, const int* in_sizes, int n_in,
                              void* d_out, int out_size, void* d_ws, size_t ws_size,
                              hipStream_t stream) {
    const float* im1 = (const float*)d_in[0];
    const float* im2 = (const float*)d_in[1];
    const float* Wq  = (const float*)d_in[2];
    const float* Wk  = (const float*)d_in[3];
    const float* Wv  = (const float*)d_in[4];
    float* out = (float*)d_out;

    _Float16* w = (_Float16*)d_ws;
    _Float16* Wqt = w;                      // 64*512
    _Float16* Wkt = Wqt + 64 * 512;
    _Float16* Wvt = Wkt + 64 * 512;         // 512*512
    _Float16* Q1  = Wvt + 512 * 512;        // 8192*64 each
    _Float16* K1  = Q1 + NN * DKK;
    _Float16* Q2  = K1 + NN * DKK;
    _Float16* K2  = Q2 + NN * DKK;
    _Float16* V1b = K2 + NN * DKK;          // kv-tiled [128][512][64] each
    _Float16* V2b = V1b + (size_t)CC * NN;

    wtrans_kernel<<<128, 256, 0, stream>>>(Wq, Wqt, 64);
    wtrans_kernel<<<128, 256, 0, stream>>>(Wk, Wkt, 64);
    wtrans_kernel<<<1024, 256, 0, stream>>>(Wv, Wvt, 512);
    proj_qk2_kernel<<<dim3(128, 2), 256, 0, stream>>>(im1, im2, Wqt, Wkt, Q1, K1, Q2, K2);
    proj_vt_kernel<<<dim3(256, 2), 256, 0, stream>>>(im1, im2, Wvt, V1b, V2b);
    flash3_kernel<<<dim3(128, 2), 512, 0, stream>>>(Q1, K1, Q2, K2, V1b, V2b, im1, im2, out);
}

// Round 4
// 437.486 us; speedup vs baseline: 1.8462x; 1.0665x over previous
//
#include <hip/hip_runtime.h>

#define NN 8192
#define CC 512
#define DKK 64

typedef float f32x4 __attribute__((ext_vector_type(4)));
typedef float f32x16 __attribute__((ext_vector_type(16)));
typedef _Float16 f16x8 __attribute__((ext_vector_type(8)));
typedef _Float16 f16x4 __attribute__((ext_vector_type(4)));

__device__ __forceinline__ f32x4 mfma16(f16x8 a, f16x8 b, f32x4 c) {
    return __builtin_amdgcn_mfma_f32_16x16x32_f16(a, b, c, 0, 0, 0);
}
__device__ __forceinline__ f32x16 mfma32(f16x8 a, f16x8 b, f32x16 c) {
    return __builtin_amdgcn_mfma_f32_32x32x16_f16(a, b, c, 0, 0, 0);
}
__device__ __forceinline__ f16x8 scl8(f16x8 v, float f) {
    _Float16 h = (_Float16)f;
    f16x8 r;
#pragma unroll
    for (int i = 0; i < 8; i++) r[i] = v[i] * h;
    return r;
}

// ---- Wq/Wk transpose: W[512][64] f32 -> Wt[64][512] f16
__global__ void wtrans_qk_kernel(const float* __restrict__ Wq, const float* __restrict__ Wk,
                                 _Float16* __restrict__ Wqt, _Float16* __restrict__ Wkt) {
    const float* W = blockIdx.y ? Wk : Wq;
    _Float16* Wt = blockIdx.y ? Wkt : Wqt;
    int idx = blockIdx.x * 256 + threadIdx.x;
    int n = idx >> 9, k = idx & 511;
    Wt[idx] = (_Float16)W[k * 64 + n];
}

// ---- Wv -> frag-major Wvf[ks=0..31][c=512][k16=16]: Wvf[(ks*512+c)*16+k16] = Wv[16ks+k16][c]
__global__ void wtransv_kernel(const float* __restrict__ W, _Float16* __restrict__ Wvf) {
    int idx = blockIdx.x * 256 + threadIdx.x;
    int k16 = idx & 15;
    int c = (idx >> 4) & 511;
    int ks = idx >> 13;
    Wvf[idx] = (_Float16)W[(size_t)(16 * ks + k16) * 512 + c];
}

// ---- fused Q+K projection: Q[N][64] row-major f16; K -> frag-major
// Kf[tile=n>>6][ks=dk>>4][kv6=n&63][k16=dk&15]
__global__ __launch_bounds__(256) void proj_qk2_kernel(
    const float* __restrict__ im1, const float* __restrict__ im2,
    const _Float16* __restrict__ Wqt, const _Float16* __restrict__ Wkt,
    _Float16* __restrict__ Q1, _Float16* __restrict__ Kf1,
    _Float16* __restrict__ Q2, _Float16* __restrict__ Kf2)
{
    const float* X = blockIdx.y ? im2 : im1;
    _Float16* Q = blockIdx.y ? Q2 : Q1;
    _Float16* Kf = blockIdx.y ? Kf2 : Kf1;

    __shared__ __align__(16) _Float16 Wlds[128 * 512];  // 128 KB

    const int tid = threadIdx.x;
    const int lane = tid & 63, wave = tid >> 6;
    const int n16 = lane & 15, quad = lane >> 4;

#pragma unroll
    for (int i = 0; i < 32; i++) {
        const int idx = tid + 256 * i;
        const int row = idx >> 6, ch = idx & 63;
        const _Float16* src = (row < 64) ? (Wqt + (size_t)row * 512 + ch * 8)
                                         : (Wkt + (size_t)(row - 64) * 512 + ch * 8);
        *(f16x8*)&Wlds[row * 512 + ((ch ^ (row & 7)) * 8)] = *(const f16x8*)src;
    }
    __syncthreads();

    const int arow = blockIdx.x * 64 + wave * 16 + n16;
    f32x4 acc[8];
#pragma unroll
    for (int i = 0; i < 8; i++) acc[i] = (f32x4){0.f, 0.f, 0.f, 0.f};

    const float* xbase = X + (size_t)arow * 512 + quad * 8;
    for (int kk = 0; kk < 16; kk++) {
        f32x4 xa = *(const f32x4*)(xbase + kk * 32);
        f32x4 xb = *(const f32x4*)(xbase + kk * 32 + 4);
        f16x8 afrag;
#pragma unroll
        for (int j = 0; j < 4; j++) { afrag[j] = (_Float16)xa[j]; afrag[4 + j] = (_Float16)xb[j]; }
#pragma unroll
        for (int t = 0; t < 8; t++) {
            const int row = t * 16 + n16;
            f16x8 bfr = *(const f16x8*)&Wlds[row * 512 + (((4 * kk + quad) ^ (row & 7)) * 8)];
            acc[t] = mfma16(afrag, bfr, acc[t]);
        }
    }
    const int rbase = blockIdx.x * 64 + wave * 16 + quad * 4;
#pragma unroll
    for (int t = 0; t < 4; t++)
#pragma unroll
        for (int r = 0; r < 4; r++) {
            Q[(size_t)(rbase + r) * 64 + t * 16 + n16] = (_Float16)acc[t][r];
            // K frag-major: tile = blockIdx.x, ks = t, kv6 = wave*16+quad*4+r, k16 = n16
            Kf[((size_t)(blockIdx.x * 4 + t) * 64 + (wave * 16 + quad * 4 + r)) * 16 + n16] =
                (_Float16)acc[4 + t][r];
        }
}

// ---- V projection -> frag-major Vf[tile][ks=n6>>4][c=512][n16]
__global__ __launch_bounds__(256) void proj_vt_kernel(
    const float* __restrict__ im1, const float* __restrict__ im2,
    const _Float16* __restrict__ Wvf,
    _Float16* __restrict__ Vf1, _Float16* __restrict__ Vf2)
{
    const float* X = blockIdx.y ? im2 : im1;
    _Float16* Vf = blockIdx.y ? Vf2 : Vf1;
    const int n0 = blockIdx.x * 32;
    const int tid = threadIdx.x;
    const int lane = tid & 63, wave = tid >> 6;
    const int l31 = lane & 31, lhi = lane >> 5;

    __shared__ __align__(16) _Float16 Xlds[32 * 512];

#pragma unroll
    for (int i = 0; i < 8; i++) {
        const int n = tid >> 3;
        const int chunk = (tid & 7) + 8 * i;
        const float* xp = X + (size_t)(n0 + n) * CC + chunk * 8;
        f32x4 x0 = *(const f32x4*)xp;
        f32x4 x1 = *(const f32x4*)(xp + 4);
        f16x8 d;
#pragma unroll
        for (int j = 0; j < 4; j++) { d[j] = (_Float16)x0[j]; d[4 + j] = (_Float16)x1[j]; }
        *(f16x8*)&Xlds[n * 512 + ((chunk ^ (n & 7)) * 8)] = d;
    }
    __syncthreads();

    f32x16 acc[4];
#pragma unroll
    for (int t = 0; t < 4; t++)
#pragma unroll
        for (int r = 0; r < 16; r++) acc[t][r] = 0.f;

    for (int ks = 0; ks < 32; ks++) {
        f16x8 xb = *(const f16x8*)&Xlds[l31 * 512 + (((2 * ks + lhi) ^ (l31 & 7)) * 8)];
#pragma unroll
        for (int ct = 0; ct < 4; ct++) {
            // dense frag-major Wv read: 32 consecutive c-rows x 32 B
            const _Float16* wp = Wvf + ((size_t)ks * 512 + 128 * wave + 32 * ct + l31) * 16 + 8 * lhi;
            acc[ct] = mfma32(*(const f16x8*)wp, xb, acc[ct]);
        }
    }
    const int tile = n0 >> 6;
    const int ksbase = (n0 & 32) >> 4;  // 0 or 2
#pragma unroll
    for (int ct = 0; ct < 4; ct++)
#pragma unroll
        for (int r = 0; r < 16; r++) {
            const int c = 128 * wave + 32 * ct + (r & 3) + 8 * (r >> 2) + 4 * lhi;
            const int ks = ksbase + (l31 >> 4);
            Vf[((size_t)(tile * 4 + ks) * 512 + c) * 16 + (l31 & 15)] = (_Float16)acc[ct][r];
        }
}

// ---- flash v4: frag-major dense L2 loads, one barrier/slot, double-buffered P,
// per-(a)-stream softmax merged lazily in PV via per-lane frag scaling.
// grid (128, 2), 512 thr = 8 waves: g = wave>>2 (kv parity), wg = wave&3;
// QK: b = wg&1 (q-half), a = wg>>1 (kv-half). PV: c-quarter 128*wg.
__global__ __launch_bounds__(512, 2) void flash4_kernel(
    const _Float16* __restrict__ Q1, const _Float16* __restrict__ Kf1,
    const _Float16* __restrict__ Q2, const _Float16* __restrict__ Kf2,
    const _Float16* __restrict__ Vf1, const _Float16* __restrict__ Vf2,
    const float* __restrict__ im1, const float* __restrict__ im2,
    float* __restrict__ out)
{
    const int img = blockIdx.y;
    const _Float16* Q = img ? Q1 : Q2;
    const _Float16* Kf = img ? Kf2 : Kf1;
    const _Float16* Vf = img ? Vf2 : Vf1;
    const float* res = img ? im2 : im1;
    float* o = out + (size_t)img * NN * CC;

    // loop: P[2 bufs][2 g][64 q][64 kv] f16 (32 KB); epilogue: Olds f32[64][516]
    __shared__ __align__(16) char smem[64 * 516 * 4];
    __shared__ float mPart[2][2][2][64];  // [buf][g][a][q]
    __shared__ float mF[2][2][64], lF[2][2][64];

    const int tid = threadIdx.x;
    const int lane = tid & 63, wave = tid >> 6;
    const int l31 = lane & 31, lhi = lane >> 5;
    const int g = wave >> 2, wg = wave & 3;
    const int b = wg & 1, a = wg >> 1;
    const int qbase = blockIdx.x * 64;
    const int swz = l31 & 7;

    _Float16* Pbase = (_Float16*)smem;

    f16x8 qf[4];
    {
        const _Float16* qp = Q + (size_t)(qbase + 32 * b + l31) * DKK + 8 * lhi;
#pragma unroll
        for (int k = 0; k < 4; k++) qf[k] = *(const f16x8*)(qp + 16 * k);
    }

    f32x16 acc[8];  // [ct*2 + qt]
#pragma unroll
    for (int t = 0; t < 8; t++)
#pragma unroll
        for (int r = 0; r < 16; r++) acc[t][r] = 0.f;
    float ma_run = -3e38f, l_run = 0.f;  // own (g,a) stream
    float mg_run[2] = {-3e38f, -3e38f};  // per qt, acc reference max

    for (int s = 0; s < 64; s++) {
        const int t = 2 * s + g;
        const int pbuf = s & 1;
        _Float16* Pg = Pbase + (pbuf * 2 + g) * 4096;

        // ---- QK: dense frag-major K loads
        f32x16 sA;
#pragma unroll
        for (int r = 0; r < 16; r++) sA[r] = 0.f;
#pragma unroll
        for (int k = 0; k < 4; k++) {
            f16x8 kf = *(const f16x8*)(Kf + ((size_t)(t * 4 + k) * 64 + 32 * a + l31) * 16 + 8 * lhi);
            sA = mfma32(kf, qf[k], sA);
        }
        float mx = -3e38f;
#pragma unroll
        for (int r = 0; r < 16; r++) mx = fmaxf(mx, sA[r]);
        mx = fmaxf(mx, __shfl_xor(mx, 32));
        const float manew = fmaxf(ma_run, mx);

        // prefetch k=0 V frags (independent of P / barrier)
        f16x8 va0[4];
#pragma unroll
        for (int ct = 0; ct < 4; ct++)
            va0[ct] = *(const f16x8*)(Vf + ((size_t)(t * 4) * 512 + 128 * wg + 32 * ct + l31) * 16 + 8 * lhi);

        float ls = 0.f;
#pragma unroll
        for (int r = 0; r < 16; r++) {
            float p = __expf(sA[r] - manew);
            ls += p;
            sA[r] = p;
        }
        ls += __shfl_xor(ls, 32);
        l_run = l_run * __expf(ma_run - manew) + ls;
        ma_run = manew;
        if (lane < 32) mPart[pbuf][g][a][32 * b + lane] = manew;
        {
            const int q = 32 * b + l31;
#pragma unroll
            for (int gg = 0; gg < 4; gg++) {
                f16x4 p4;
#pragma unroll
                for (int u = 0; u < 4; u++) p4[u] = (_Float16)sA[gg * 4 + u];
                *(f16x4*)&Pg[q * 64 + (((4 * a + gg) ^ (q & 7)) * 8) + 4 * lhi] = p4;
            }
        }
        __syncthreads();  // the only barrier per slot

        // ---- PV: merge a-streams lazily; dense frag-major V loads
        float al[2], f0[2], f1[2];
#pragma unroll
        for (int qt = 0; qt < 2; qt++) {
            const int q = 32 * qt + l31;
            const float m0 = mPart[pbuf][g][0][q];
            const float m1 = mPart[pbuf][g][1][q];
            const float mgn = fmaxf(mg_run[qt], fmaxf(m0, m1));
            al[qt] = __expf(mg_run[qt] - mgn);
            f0[qt] = __expf(m0 - mgn);
            f1[qt] = __expf(m1 - mgn);
            mg_run[qt] = mgn;
        }
        if (!__all((al[0] == 1.f) & (al[1] == 1.f))) {
#pragma unroll
            for (int ct = 0; ct < 4; ct++)
#pragma unroll
                for (int r = 0; r < 16; r++) {
                    acc[ct * 2 + 0][r] *= al[0];
                    acc[ct * 2 + 1][r] *= al[1];
                }
        }
        const bool noscale =
            __all((f0[0] == 1.f) & (f1[0] == 1.f) & (f0[1] == 1.f) & (f1[1] == 1.f));
#pragma unroll
        for (int k = 0; k < 4; k++) {
            const int psw = ((2 * k + lhi) ^ swz) * 8;
            f16x8 pb0 = *(const f16x8*)&Pg[l31 * 64 + psw];
            f16x8 pb1 = *(const f16x8*)&Pg[(32 + l31) * 64 + psw];
            if (!noscale) {
                pb0 = scl8(pb0, k < 2 ? f0[0] : f1[0]);
                pb1 = scl8(pb1, k < 2 ? f0[1] : f1[1]);
            }
#pragma unroll
            for (int ct = 0; ct < 4; ct++) {
                f16x8 va;
                if (k == 0) va = va0[ct];
                else va = *(const f16x8*)(Vf + ((size_t)(t * 4 + k) * 512 + 128 * wg + 32 * ct + l31) * 16 + 8 * lhi);
                acc[ct * 2 + 0] = mfma32(va, pb0, acc[ct * 2 + 0]);
                acc[ct * 2 + 1] = mfma32(va, pb1, acc[ct * 2 + 1]);
            }
        }
        // next slot writes the other P buffer; no second barrier needed
    }

    // ---- epilogue: merge 4 (g,a) streams, add residual, store
    if (lane < 32) {
        mF[g][a][32 * b + lane] = ma_run;
        lF[g][a][32 * b + lane] = l_run;
    }
    __syncthreads();

    float fac[2];
#pragma unroll
    for (int qt = 0; qt < 2; qt++) {
        const int q = 32 * qt + l31;
        const float m00 = mF[0][0][q], m01 = mF[0][1][q];
        const float m10 = mF[1][0][q], m11 = mF[1][1][q];
        const float M = fmaxf(fmaxf(m00, m01), fmaxf(m10, m11));
        const float den = lF[0][0][q] * __expf(m00 - M) + lF[0][1][q] * __expf(m01 - M) +
                          lF[1][0][q] * __expf(m10 - M) + lF[1][1][q] * __expf(m11 - M);
        fac[qt] = __expf(mg_run[qt] - M) / den;
    }

    float* Olds = (float*)smem;  // [64][516]
    if (g == 0) {
#pragma unroll
        for (int ct = 0; ct < 4; ct++)
#pragma unroll
            for (int qt = 0; qt < 2; qt++)
#pragma unroll
                for (int r = 0; r < 16; r++) {
                    const int c = 128 * wg + 32 * ct + (r & 3) + 8 * (r >> 2) + 4 * lhi;
                    Olds[(32 * qt + l31) * 516 + c] = acc[ct * 2 + qt][r] * fac[qt];
                }
    }
    __syncthreads();
    if (g == 1) {
#pragma unroll
        for (int ct = 0; ct < 4; ct++)
#pragma unroll
            for (int qt = 0; qt < 2; qt++)
#pragma unroll
                for (int r = 0; r < 16; r++) {
                    const int c = 128 * wg + 32 * ct + (r & 3) + 8 * (r >> 2) + 4 * lhi;
                    Olds[(32 * qt + l31) * 516 + c] += acc[ct * 2 + qt][r] * fac[qt];
                }
    }
    __syncthreads();

    {
        const int q = tid >> 3;
        const size_t grow = (size_t)(qbase + q);
#pragma unroll
        for (int i = 0; i < 16; i++) {
            const int cw = ((tid & 7) + 8 * i) * 4;
            f32x4 v = *(const f32x4*)&Olds[q * 516 + cw];
            f32x4 rr = *(const f32x4*)(res + grow * CC + cw);
            v += rr;
            *(f32x4*)(o + grow * CC + cw) = v;
        }
    }
}

extern "C" void kernel_launch(void* const* d_in, const int* in_sizes, int n_in,
                              void* d_out, int out_size, void* d_ws, size_t ws_size,
                              hipStream_t stream) {
    const float* im1 = (const float*)d_in[0];
    const float* im2 = (const float*)d_in[1];
    const float* Wq  = (const float*)d_in[2];
    const float* Wk  = (const float*)d_in[3];
    const float* Wv  = (const float*)d_in[4];
    float* out = (float*)d_out;

    _Float16* w = (_Float16*)d_ws;
    _Float16* Wqt = w;                      // 64*512
    _Float16* Wkt = Wqt + 64 * 512;
    _Float16* Wvf = Wkt + 64 * 512;         // 512*512 frag-major
    _Float16* Q1  = Wvf + 512 * 512;        // 8192*64 each
    _Float16* Kf1 = Q1 + NN * DKK;
    _Float16* Q2  = Kf1 + NN * DKK;
    _Float16* Kf2 = Q2 + NN * DKK;
    _Float16* Vf1 = Kf2 + NN * DKK;         // frag-major [128][4][512][16] each
    _Float16* Vf2 = Vf1 + (size_t)CC * NN;

    wtrans_qk_kernel<<<dim3(128, 2), 256, 0, stream>>>(Wq, Wk, Wqt, Wkt);
    wtransv_kernel<<<1024, 256, 0, stream>>>(Wv, Wvf);
    proj_qk2_kernel<<<dim3(128, 2), 256, 0, stream>>>(im1, im2, Wqt, Wkt, Q1, Kf1, Q2, Kf2);
    proj_vt_kernel<<<dim3(256, 2), 256, 0, stream>>>(im1, im2, Wvf, Vf1, Vf2);
    flash4_kernel<<<dim3(128, 2), 512, 0, stream>>>(Q1, Kf1, Q2, Kf2, Vf1, Vf2, im1, im2, out);
}

// Round 7
// 421.954 us; speedup vs baseline: 1.9141x; 1.0368x over previous
//
#include <hip/hip_runtime.h>

#define NN 8192
#define CC 512
#define DKK 64

typedef float f32x4 __attribute__((ext_vector_type(4)));
typedef float f32x16 __attribute__((ext_vector_type(16)));
typedef _Float16 f16x8 __attribute__((ext_vector_type(8)));
typedef _Float16 f16x4 __attribute__((ext_vector_type(4)));

__device__ __forceinline__ f32x4 mfma16(f16x8 a, f16x8 b, f32x4 c) {
    return __builtin_amdgcn_mfma_f32_16x16x32_f16(a, b, c, 0, 0, 0);
}
__device__ __forceinline__ f32x16 mfma32(f16x8 a, f16x8 b, f32x16 c) {
    return __builtin_amdgcn_mfma_f32_32x32x16_f16(a, b, c, 0, 0, 0);
}
__device__ __forceinline__ f16x8 scl8(f16x8 v, float f) {
    _Float16 h = (_Float16)f;
    f16x8 r;
#pragma unroll
    for (int i = 0; i < 8; i++) r[i] = v[i] * h;
    return r;
}

// ---- all weight transposes in one launch. grid 1280 x 256.
// Wqt: 64*512 = 32768; Wkt: 32768; Wvf: 512*512 = 262144. Total 327680.
__global__ void wtrans_all_kernel(const float* __restrict__ Wq, const float* __restrict__ Wk,
                                  const float* __restrict__ Wv,
                                  _Float16* __restrict__ Wqt, _Float16* __restrict__ Wkt,
                                  _Float16* __restrict__ Wvf) {
    int idx = blockIdx.x * 256 + threadIdx.x;
    if (idx < 32768) {
        int n = idx >> 9, k = idx & 511;
        Wqt[idx] = (_Float16)Wq[k * 64 + n];
    } else if (idx < 65536) {
        int j = idx - 32768;
        int n = j >> 9, k = j & 511;
        Wkt[j] = (_Float16)Wk[k * 64 + n];
    } else {
        int j = idx - 65536;
        int k16 = j & 15, c = (j >> 4) & 511, ks = j >> 13;
        Wvf[j] = (_Float16)Wv[(size_t)(16 * ks + k16) * 512 + c];
    }
}

// ---- fused Q+K projection: Q[N][64] row-major f16; K -> frag-major
// Kf[tile=n>>6][ks=dk>>4][kv6=n&63][k16=dk&15]
__global__ __launch_bounds__(256) void proj_qk2_kernel(
    const float* __restrict__ im1, const float* __restrict__ im2,
    const _Float16* __restrict__ Wqt, const _Float16* __restrict__ Wkt,
    _Float16* __restrict__ Q1, _Float16* __restrict__ Kf1,
    _Float16* __restrict__ Q2, _Float16* __restrict__ Kf2)
{
    const float* X = blockIdx.y ? im2 : im1;
    _Float16* Q = blockIdx.y ? Q2 : Q1;
    _Float16* Kf = blockIdx.y ? Kf2 : Kf1;

    __shared__ __align__(16) _Float16 Wlds[128 * 512];  // 128 KB

    const int tid = threadIdx.x;
    const int lane = tid & 63, wave = tid >> 6;
    const int n16 = lane & 15, quad = lane >> 4;

#pragma unroll
    for (int i = 0; i < 32; i++) {
        const int idx = tid + 256 * i;
        const int row = idx >> 6, ch = idx & 63;
        const _Float16* src = (row < 64) ? (Wqt + (size_t)row * 512 + ch * 8)
                                         : (Wkt + (size_t)(row - 64) * 512 + ch * 8);
        *(f16x8*)&Wlds[row * 512 + ((ch ^ (row & 7)) * 8)] = *(const f16x8*)src;
    }
    __syncthreads();

    const int arow = blockIdx.x * 64 + wave * 16 + n16;
    f32x4 acc[8];
#pragma unroll
    for (int i = 0; i < 8; i++) acc[i] = (f32x4){0.f, 0.f, 0.f, 0.f};

    const float* xbase = X + (size_t)arow * 512 + quad * 8;
    for (int kk = 0; kk < 16; kk++) {
        f32x4 xa = *(const f32x4*)(xbase + kk * 32);
        f32x4 xb = *(const f32x4*)(xbase + kk * 32 + 4);
        f16x8 afrag;
#pragma unroll
        for (int j = 0; j < 4; j++) { afrag[j] = (_Float16)xa[j]; afrag[4 + j] = (_Float16)xb[j]; }
#pragma unroll
        for (int t = 0; t < 8; t++) {
            const int row = t * 16 + n16;
            f16x8 bfr = *(const f16x8*)&Wlds[row * 512 + (((4 * kk + quad) ^ (row & 7)) * 8)];
            acc[t] = mfma16(afrag, bfr, acc[t]);
        }
    }
    const int rbase = blockIdx.x * 64 + wave * 16 + quad * 4;
#pragma unroll
    for (int t = 0; t < 4; t++)
#pragma unroll
        for (int r = 0; r < 4; r++) {
            Q[(size_t)(rbase + r) * 64 + t * 16 + n16] = (_Float16)acc[t][r];
            Kf[((size_t)(blockIdx.x * 4 + t) * 64 + (wave * 16 + quad * 4 + r)) * 16 + n16] =
                (_Float16)acc[4 + t][r];
        }
}

// ---- V projection -> frag-major Vf[tile][ks=n6>>4][c=512][n16]
__global__ __launch_bounds__(256) void proj_vt_kernel(
    const float* __restrict__ im1, const float* __restrict__ im2,
    const _Float16* __restrict__ Wvf,
    _Float16* __restrict__ Vf1, _Float16* __restrict__ Vf2)
{
    const float* X = blockIdx.y ? im2 : im1;
    _Float16* Vf = blockIdx.y ? Vf2 : Vf1;
    const int n0 = blockIdx.x * 32;
    const int tid = threadIdx.x;
    const int lane = tid & 63, wave = tid >> 6;
    const int l31 = lane & 31, lhi = lane >> 5;

    __shared__ __align__(16) _Float16 Xlds[32 * 512];

#pragma unroll
    for (int i = 0; i < 8; i++) {
        const int n = tid >> 3;
        const int chunk = (tid & 7) + 8 * i;
        const float* xp = X + (size_t)(n0 + n) * CC + chunk * 8;
        f32x4 x0 = *(const f32x4*)xp;
        f32x4 x1 = *(const f32x4*)(xp + 4);
        f16x8 d;
#pragma unroll
        for (int j = 0; j < 4; j++) { d[j] = (_Float16)x0[j]; d[4 + j] = (_Float16)x1[j]; }
        *(f16x8*)&Xlds[n * 512 + ((chunk ^ (n & 7)) * 8)] = d;
    }
    __syncthreads();

    f32x16 acc[4];
#pragma unroll
    for (int t = 0; t < 4; t++)
#pragma unroll
        for (int r = 0; r < 16; r++) acc[t][r] = 0.f;

    for (int ks = 0; ks < 32; ks++) {
        f16x8 xb = *(const f16x8*)&Xlds[l31 * 512 + (((2 * ks + lhi) ^ (l31 & 7)) * 8)];
#pragma unroll
        for (int ct = 0; ct < 4; ct++) {
            const _Float16* wp = Wvf + ((size_t)ks * 512 + 128 * wave + 32 * ct + l31) * 16 + 8 * lhi;
            acc[ct] = mfma32(*(const f16x8*)wp, xb, acc[ct]);
        }
    }
    const int tile = n0 >> 6;
    const int ksbase = (n0 & 32) >> 4;  // 0 or 2
#pragma unroll
    for (int ct = 0; ct < 4; ct++)
#pragma unroll
        for (int r = 0; r < 16; r++) {
            const int c = 128 * wave + 32 * ct + (r & 3) + 8 * (r >> 2) + 4 * lhi;
            const int ks = ksbase + (l31 >> 4);
            Vf[((size_t)(tile * 4 + ks) * 512 + c) * 16 + (l31 & 15)] = (_Float16)acc[ct][r];
        }
}

// ---- flash v5: QK pipelined one slot ahead of PV, one barrier/slot,
// chunk-major P (conflict-free), frag-major dense K/V loads from L2.
// grid (128, 2), 512 thr = 8 waves: g = wave>>2 (kv parity), wg = wave&3;
// QK: b = wg&1 (q-half), a = wg>>1 (kv-half). PV: c-quarter 128*wg.
__global__ __launch_bounds__(512, 2) void flash5_kernel(
    const _Float16* __restrict__ Q1, const _Float16* __restrict__ Kf1,
    const _Float16* __restrict__ Q2, const _Float16* __restrict__ Kf2,
    const _Float16* __restrict__ Vf1, const _Float16* __restrict__ Vf2,
    const float* __restrict__ im1, const float* __restrict__ im2,
    float* __restrict__ out)
{
    const int img = blockIdx.y;
    const _Float16* Q = img ? Q1 : Q2;
    const _Float16* Kf = img ? Kf2 : Kf1;
    const _Float16* Vf = img ? Vf2 : Vf1;
    const float* res = img ? im2 : im1;
    float* o = out + (size_t)img * NN * CC;

    // loop: P[2 bufs][2 g][8 chunk][64 q][8] f16 (32 KB); epilogue: Olds f32[64][516]
    __shared__ __align__(16) char smem[64 * 516 * 4];
    __shared__ float mPart[2][2][2][64];  // [buf][g][a][q]
    __shared__ float mF[2][2][64], lF[2][2][64];

    const int tid = threadIdx.x;
    const int lane = tid & 63, wave = tid >> 6;
    const int l31 = lane & 31, lhi = lane >> 5;
    const int g = wave >> 2, wg = wave & 3;
    const int b = wg & 1, a = wg >> 1;
    const int qbase = blockIdx.x * 64;

    _Float16* Pbase = (_Float16*)smem;

    f16x8 qf[4];
    {
        const _Float16* qp = Q + (size_t)(qbase + 32 * b + l31) * DKK + 8 * lhi;
#pragma unroll
        for (int k = 0; k < 4; k++) qf[k] = *(const f16x8*)(qp + 16 * k);
    }

    f32x16 acc[8];  // [ct*2 + qt]
#pragma unroll
    for (int t = 0; t < 8; t++)
#pragma unroll
        for (int r = 0; r < 16; r++) acc[t][r] = 0.f;
    float ma_run = -3e38f, l_run = 0.f;  // own (g,a) stream
    float mg_run[2] = {-3e38f, -3e38f};  // per qt, acc reference max

    // QK for slot s: compute S^T quarter, softmax vs own stream, write P+mPart.
    auto do_qk = [&](int s) {
        const int t = 2 * s + g;
        const int pbuf = s & 1;
        _Float16* Pg = Pbase + (pbuf * 2 + g) * 4096;
        f32x16 sA;
#pragma unroll
        for (int r = 0; r < 16; r++) sA[r] = 0.f;
#pragma unroll
        for (int k = 0; k < 4; k++) {
            f16x8 kf = *(const f16x8*)(Kf + ((size_t)(t * 4 + k) * 64 + 32 * a + l31) * 16 + 8 * lhi);
            sA = mfma32(kf, qf[k], sA);
        }
        float mx = -3e38f;
#pragma unroll
        for (int r = 0; r < 16; r++) mx = fmaxf(mx, sA[r]);
        mx = fmaxf(mx, __shfl_xor(mx, 32));
        const float manew = fmaxf(ma_run, mx);
        if (lane < 32) mPart[pbuf][g][a][32 * b + lane] = manew;
        float ls = 0.f;
#pragma unroll
        for (int r = 0; r < 16; r++) {
            float p = __expf(sA[r] - manew);
            ls += p;
            sA[r] = p;
        }
        ls += __shfl_xor(ls, 32);
        l_run = l_run * __expf(ma_run - manew) + ls;
        ma_run = manew;
        const int q = 32 * b + l31;
#pragma unroll
        for (int gg = 0; gg < 4; gg++) {
            f16x4 p4;
#pragma unroll
            for (int u = 0; u < 4; u++) p4[u] = (_Float16)sA[gg * 4 + u];
            // chunk-major: P[chunk=4a+gg][q][8], lane offset 4*lhi (contiguous, 0-conflict)
            *(f16x4*)&Pg[((4 * a + gg) * 64 + q) * 8 + 4 * lhi] = p4;
        }
    };

    do_qk(0);
    __syncthreads();

    for (int s = 0; s < 64; s++) {
        const int t = 2 * s + g;
        const int pbuf = s & 1;
        _Float16* Pg = Pbase + (pbuf * 2 + g) * 4096;

        // early V-frag issue for PV(s), k = 0,1 (covers L2 latency under QK(s+1))
        f16x8 va01[8];
#pragma unroll
        for (int k = 0; k < 2; k++)
#pragma unroll
            for (int ct = 0; ct < 4; ct++)
                va01[k * 4 + ct] = *(const f16x8*)(Vf +
                    ((size_t)(t * 4 + k) * 512 + 128 * wg + 32 * ct + l31) * 16 + 8 * lhi);

        // pipelined QK for next slot (writes other P buffer)
        if (s < 63) do_qk(s + 1);

        // ---- PV(s): merge a-streams lazily; dense frag-major V loads
        float al[2], f0[2], f1[2];
#pragma unroll
        for (int qt = 0; qt < 2; qt++) {
            const int q = 32 * qt + l31;
            const float m0 = mPart[pbuf][g][0][q];
            const float m1 = mPart[pbuf][g][1][q];
            const float mgn = fmaxf(mg_run[qt], fmaxf(m0, m1));
            al[qt] = __expf(mg_run[qt] - mgn);
            f0[qt] = __expf(m0 - mgn);
            f1[qt] = __expf(m1 - mgn);
            mg_run[qt] = mgn;
        }
        if (!__all((al[0] == 1.f) & (al[1] == 1.f))) {
#pragma unroll
            for (int ct = 0; ct < 4; ct++)
#pragma unroll
                for (int r = 0; r < 16; r++) {
                    acc[ct * 2 + 0][r] *= al[0];
                    acc[ct * 2 + 1][r] *= al[1];
                }
        }
        const bool noscale =
            __all((f0[0] == 1.f) & (f1[0] == 1.f) & (f0[1] == 1.f) & (f1[1] == 1.f));
#pragma unroll
        for (int k = 0; k < 4; k++) {
            // chunk-major P reads: lanes contiguous, 0-conflict
            f16x8 pb0 = *(const f16x8*)&Pg[((2 * k + lhi) * 64 + l31) * 8];
            f16x8 pb1 = *(const f16x8*)&Pg[((2 * k + lhi) * 64 + 32 + l31) * 8];
            if (!noscale) {
                pb0 = scl8(pb0, k < 2 ? f0[0] : f1[0]);
                pb1 = scl8(pb1, k < 2 ? f0[1] : f1[1]);
            }
#pragma unroll
            for (int ct = 0; ct < 4; ct++) {
                f16x8 va;
                if (k < 2) va = va01[k * 4 + ct];
                else va = *(const f16x8*)(Vf +
                    ((size_t)(t * 4 + k) * 512 + 128 * wg + 32 * ct + l31) * 16 + 8 * lhi);
                acc[ct * 2 + 0] = mfma32(va, pb0, acc[ct * 2 + 0]);
                acc[ct * 2 + 1] = mfma32(va, pb1, acc[ct * 2 + 1]);
            }
        }
        __syncthreads();  // P(s+1)/mPart written by all; P(s) reads done
    }

    // ---- epilogue: merge 4 (g,a) streams, add residual, store
    if (lane < 32) {
        mF[g][a][32 * b + lane] = ma_run;
        lF[g][a][32 * b + lane] = l_run;
    }
    __syncthreads();

    float fac[2];
#pragma unroll
    for (int qt = 0; qt < 2; qt++) {
        const int q = 32 * qt + l31;
        const float m00 = mF[0][0][q], m01 = mF[0][1][q];
        const float m10 = mF[1][0][q], m11 = mF[1][1][q];
        const float M = fmaxf(fmaxf(m00, m01), fmaxf(m10, m11));
        const float den = lF[0][0][q] * __expf(m00 - M) + lF[0][1][q] * __expf(m01 - M) +
                          lF[1][0][q] * __expf(m10 - M) + lF[1][1][q] * __expf(m11 - M);
        fac[qt] = __expf(mg_run[qt] - M) / den;
    }

    float* Olds = (float*)smem;  // [64][516]
    if (g == 0) {
#pragma unroll
        for (int ct = 0; ct < 4; ct++)
#pragma unroll
            for (int qt = 0; qt < 2; qt++)
#pragma unroll
                for (int r = 0; r < 16; r++) {
                    const int c = 128 * wg + 32 * ct + (r & 3) + 8 * (r >> 2) + 4 * lhi;
                    Olds[(32 * qt + l31) * 516 + c] = acc[ct * 2 + qt][r] * fac[qt];
                }
    }
    __syncthreads();
    if (g == 1) {
#pragma unroll
        for (int ct = 0; ct < 4; ct++)
#pragma unroll
            for (int qt = 0; qt < 2; qt++)
#pragma unroll
                for (int r = 0; r < 16; r++) {
                    const int c = 128 * wg + 32 * ct + (r & 3) + 8 * (r >> 2) + 4 * lhi;
                    Olds[(32 * qt + l31) * 516 + c] += acc[ct * 2 + qt][r] * fac[qt];
                }
    }
    __syncthreads();

    {
        const int q = tid >> 3;
        const size_t grow = (size_t)(qbase + q);
#pragma unroll
        for (int i = 0; i < 16; i++) {
            const int cw = ((tid & 7) + 8 * i) * 4;
            f32x4 v = *(const f32x4*)&Olds[q * 516 + cw];
            f32x4 rr = *(const f32x4*)(res + grow * CC + cw);
            v += rr;
            *(f32x4*)(o + grow * CC + cw) = v;
        }
    }
}

extern "C" void kernel_launch(void* const* d_in, const int* in_sizes, int n_in,
                              void* d_out, int out_size, void* d_ws, size_t ws_size,
                              hipStream_t stream) {
    const float* im1 = (const float*)d_in[0];
    const float* im2 = (const float*)d_in[1];
    const float* Wq  = (const float*)d_in[2];
    const float* Wk  = (const float*)d_in[3];
    const float* Wv  = (const float*)d_in[4];
    float* out = (float*)d_out;

    _Float16* w = (_Float16*)d_ws;
    _Float16* Wqt = w;                      // 64*512
    _Float16* Wkt = Wqt + 64 * 512;
    _Float16* Wvf = Wkt + 64 * 512;         // 512*512 frag-major
    _Float16* Q1  = Wvf + 512 * 512;        // 8192*64 each
    _Float16* Kf1 = Q1 + NN * DKK;
    _Float16* Q2  = Kf1 + NN * DKK;
    _Float16* Kf2 = Q2 + NN * DKK;
    _Float16* Vf1 = Kf2 + NN * DKK;         // frag-major [128][4][512][16] each
    _Float16* Vf2 = Vf1 + (size_t)CC * NN;

    wtrans_all_kernel<<<1280, 256, 0, stream>>>(Wq, Wk, Wv, Wqt, Wkt, Wvf);
    proj_qk2_kernel<<<dim3(128, 2), 256, 0, stream>>>(im1, im2, Wqt, Wkt, Q1, Kf1, Q2, Kf2);
    proj_vt_kernel<<<dim3(256, 2), 256, 0, stream>>>(im1, im2, Wvf, Vf1, Vf2);
    flash5_kernel<<<dim3(128, 2), 512, 0, stream>>>(Q1, Kf1, Q2, Kf2, Vf1, Vf2, im1, im2, out);
}